// Round 2
// baseline (5132.039 us; speedup 1.0000x reference)
//
#include <hip/hip_runtime.h>
#include <hip/hip_bf16.h>

// Problem constants
#define SEQL 4096
#define VECT 300
#define DP   320     // padded feature dim (k-dim), 10 chunks of 32
#define NQT  20      // n-tiles (320 cols) for projection GEMMs
#define HN   128
#define G3   384     // 3*H

typedef unsigned short u16;
typedef __attribute__((ext_vector_type(8))) short bf16x8;  // 8 bf16 = 4 VGPRs
typedef __attribute__((ext_vector_type(4))) float f32x4;

#define MFMA(a,b,c) __builtin_amdgcn_mfma_f32_16x16x32_bf16(a,b,c,0,0,0)
// Verified layouts (learn_hip m89/m91/m120):
//   A[m][k]: m=lane&15, k=(lane>>4)*8+j
//   B[k][n]: n=lane&15, k=(lane>>4)*8+j
//   C/D[row][col]: col=lane&15, row=(lane>>4)*4+reg

__device__ __forceinline__ u16 f2bf(float f){
    union { float f; unsigned u; } t; t.f = f;
    return (u16)((t.u + 0x7FFFu + ((t.u >> 16) & 1u)) >> 16);
}

// ---------------- fp32 [R][C] -> bf16 padded [Rp][Cp]
__global__ __launch_bounds__(256) void cvt_pad(const float* __restrict__ src,
                                               u16* __restrict__ dst,
                                               int R, int C, int Rp, int Cp)
{
    int n = Rp * Cp;
    for (int i = blockIdx.x * blockDim.x + threadIdx.x; i < n; i += gridDim.x * blockDim.x){
        int r = i / Cp, c = i - r * Cp;
        float v = (r < R && c < C) ? src[r * C + c] : 0.f;
        dst[i] = f2bf(v);
    }
}

// ---------------- x: fp32 [S][300] -> XF fp32 [S][320] + CUR bf16 [S][320]
__global__ __launch_bounds__(256) void pad_x(const float* __restrict__ src,
                                             float* __restrict__ xf, u16* __restrict__ cur)
{
    int n = SEQL * DP;
    for (int i = blockIdx.x * blockDim.x + threadIdx.x; i < n; i += gridDim.x * blockDim.x){
        int r = i / DP, c = i - r * DP;
        float v = (c < VECT) ? src[r * VECT + c] : 0.f;
        xf[i]  = v;
        cur[i] = f2bf(v);
    }
}

// ---------------- GEMM: Y[s][i][col] = sum_d A[s][i][d] * W[wsel][col][d] + bias[col]
// 256 thr = 4 waves; wave handles 32 rows (2 m-tiles); WG = 128 rows.
// OM: 0 = bf16 row-major, 1 = fp32 row-major, 2 = bf16 transposed (VT[s][col][row])
template<int NT, int OM, bool WPERSEQ>
__global__ __launch_bounds__(256) void gemm_k(
    const u16* __restrict__ A, const u16* __restrict__ Wp,
    const float* __restrict__ b0, const float* __restrict__ b1, const float* __restrict__ b2,
    int nb, void* __restrict__ Out)
{
    const int lane = threadIdx.x & 63;
    const int wid  = threadIdx.x >> 6;
    const int s    = blockIdx.z;
    const int sl   = blockIdx.y;
    const int wsel = WPERSEQ ? s : sl;
    const int row0 = blockIdx.x * 128 + wid * 32;
    const int m    = lane & 15;
    const int q    = lane >> 4;

    const u16* Arow = A + ((long)s * SEQL + row0) * DP;
    const u16* W    = Wp + (long)wsel * (NT * 16) * DP;

    f32x4 zf = {0.f, 0.f, 0.f, 0.f};
    f32x4 acc[2][NT];
    #pragma unroll
    for (int i = 0; i < 2; i++)
        #pragma unroll
        for (int n = 0; n < NT; n++) acc[i][n] = zf;

    for (int c = 0; c < DP / 32; ++c){
        const int koff = c * 32 + q * 8;
        bf16x8 a0 = *(const bf16x8*)(Arow + (m     ) * DP + koff);
        bf16x8 a1 = *(const bf16x8*)(Arow + (m + 16) * DP + koff);
        #pragma unroll
        for (int n = 0; n < NT; n++){
            bf16x8 b = *(const bf16x8*)(W + (n * 16 + m) * DP + koff);
            acc[0][n] = MFMA(a0, b, acc[0][n]);
            acc[1][n] = MFMA(a1, b, acc[1][n]);
        }
    }

    const int bsel = WPERSEQ ? s : sl;
    const float* bp = (bsel == 0) ? b0 : ((bsel == 1) ? b1 : b2);

    #pragma unroll
    for (int n = 0; n < NT; n++){
        int col = n * 16 + m;
        float bv = (col < nb) ? bp[col] : 0.f;
        #pragma unroll
        for (int i = 0; i < 2; i++){
            #pragma unroll
            for (int r = 0; r < 4; r++){
                long row = row0 + i * 16 + q * 4 + r;
                float v = acc[i][n][r] + bv;
                long off;
                if (OM == 2) off = ((long)s * DP + col) * SEQL + row;
                else         off = ((long)((WPERSEQ ? 0 : sl) * 2 + s) * SEQL + row) * (long)(NT * 16) + col;
                if (OM == 1) ((float*)Out)[off] = v;
                else         ((u16*)Out)[off]   = f2bf(v);
            }
        }
    }
}

// ---------------- flash attention: O = softmax(Q K^T / sqrt(300)) V, fp32 out
// WG 256 = 4 waves, wave owns 16 Q-rows. Online softmax over 32-col steps.
__global__ __launch_bounds__(256) void flash_k(
    const u16* __restrict__ Q, const u16* __restrict__ K, const u16* __restrict__ VT,
    float* __restrict__ O)
{
    const int lane = threadIdx.x & 63;
    const int wid  = threadIdx.x >> 6;
    const int s    = blockIdx.z;
    const int row0 = blockIdx.x * 64 + wid * 16;
    const int m = lane & 15, q = lane >> 4;

    __shared__ __align__(16) u16 pbuf_all[4][16 * 72];  // per-wave P buffer, row stride 72
    u16* pbuf = pbuf_all[wid];

    const u16* Qb  = Q  + ((long)s * SEQL + row0) * DP;
    const u16* Kb  = K  + (long)s * SEQL * DP;
    const u16* VTb = VT + (long)s * DP * SEQL;

    bf16x8 qf[10];
    #pragma unroll
    for (int c = 0; c < 10; c++)
        qf[c] = *(const bf16x8*)(Qb + m * DP + c * 32 + q * 8);

    f32x4 zf = {0.f, 0.f, 0.f, 0.f};
    f32x4 oacc[NQT];
    #pragma unroll
    for (int n = 0; n < NQT; n++) oacc[n] = zf;
    float mrow[4], lrow[4];
    #pragma unroll
    for (int r = 0; r < 4; r++){ mrow[r] = -1e30f; lrow[r] = 0.f; }

    const float scale = 0.057735026918962576f;  // 1/sqrt(300)

    for (int j = 0; j < SEQL / 32; j++){
        f32x4 sA = zf, sB = zf;
        #pragma unroll
        for (int c = 0; c < 10; c++){
            const int koff = c * 32 + q * 8;
            bf16x8 kA = *(const bf16x8*)(Kb + (long)(j * 32 +      m) * DP + koff);
            bf16x8 kB = *(const bf16x8*)(Kb + (long)(j * 32 + 16 + m) * DP + koff);
            sA = MFMA(qf[c], kA, sA);
            sB = MFMA(qf[c], kB, sB);
        }
        float alpha[4];
        #pragma unroll
        for (int r = 0; r < 4; r++){
            float a = sA[r] * scale, b = sB[r] * scale;
            float v = fmaxf(a, b);
            v = fmaxf(v, __shfl_xor(v, 1));
            v = fmaxf(v, __shfl_xor(v, 2));
            v = fmaxf(v, __shfl_xor(v, 4));
            v = fmaxf(v, __shfl_xor(v, 8));
            float mn = fmaxf(mrow[r], v);
            alpha[r] = __expf(mrow[r] - mn);
            mrow[r] = mn;
            a = __expf(a - mn);  b = __expf(b - mn);
            sA[r] = a; sB[r] = b;
            float t = a + b;
            t += __shfl_xor(t, 1); t += __shfl_xor(t, 2);
            t += __shfl_xor(t, 4); t += __shfl_xor(t, 8);
            lrow[r] = lrow[r] * alpha[r] + t;
        }
        #pragma unroll
        for (int n = 0; n < NQT; n++)
            #pragma unroll
            for (int r = 0; r < 4; r++) oacc[n][r] *= alpha[r];

        // P (C-layout) -> LDS -> A-layout
        #pragma unroll
        for (int r = 0; r < 4; r++){
            pbuf[(q * 4 + r) * 72 +      m] = f2bf(sA[r]);
            pbuf[(q * 4 + r) * 72 + 16 + m] = f2bf(sB[r]);
        }
        asm volatile("s_waitcnt lgkmcnt(0)" ::: "memory");
        bf16x8 pf = *(const bf16x8*)(pbuf + m * 72 + q * 8);

        #pragma unroll
        for (int n = 0; n < NQT; n++){
            bf16x8 vb = *(const bf16x8*)(VTb + (long)(n * 16 + m) * SEQL + j * 32 + q * 8);
            oacc[n] = MFMA(pf, vb, oacc[n]);
        }
    }

    float inv[4];
    #pragma unroll
    for (int r = 0; r < 4; r++) inv[r] = 1.f / lrow[r];
    float* Ob = O + ((long)s * SEQL + row0) * DP;
    #pragma unroll
    for (int n = 0; n < NQT; n++)
        #pragma unroll
        for (int r = 0; r < 4; r++)
            Ob[(long)(q * 4 + r) * DP + n * 16 + m] = oacc[n][r] * inv[r];
}

// ---------------- LayerNorm: out = LN(Xf + Res) * g + b
// Xf fp32 [2S][DP]; Res fp32 rows (Res0 for seq0, Res1 for seq1), stride rstride.
// OutB bf16 [2S][DP] (pads zeroed); OutF optional fp32 [2S][DP].
__global__ __launch_bounds__(256) void ln_k(const float* __restrict__ Xf,
                                            const float* __restrict__ Res0, const float* __restrict__ Res1,
                                            int rstride,
                                            const float* __restrict__ g, const float* __restrict__ b,
                                            u16* __restrict__ OutB, float* __restrict__ OutF)
{
    long row = (long)((blockIdx.x * blockDim.x + threadIdx.x) >> 6);
    int lane = threadIdx.x & 63;
    if (row >= 2L * SEQL) return;
    const float* xr = Xf + row * DP;
    const float* rr = (row < SEQL) ? (Res0 + row * (long)rstride)
                                   : (Res1 + (row - SEQL) * (long)rstride);
    float v[5], sum = 0.f, sq = 0.f;
    #pragma unroll
    for (int i = 0; i < 5; i++){
        int c = lane + i * 64;
        float t = (c < VECT) ? (xr[c] + rr[c]) : 0.f;
        v[i] = t; sum += t; sq += t * t;
    }
    #pragma unroll
    for (int o = 1; o < 64; o <<= 1){ sum += __shfl_xor(sum, o); sq += __shfl_xor(sq, o); }
    float mean = sum / VECT;
    float var  = sq / VECT - mean * mean;
    float rstd = rsqrtf(var + 1e-5f);
    #pragma unroll
    for (int i = 0; i < 5; i++){
        int c = lane + i * 64;
        float t = (c < VECT) ? ((v[i] - mean) * rstd * g[c] + b[c]) : 0.f;
        OutB[row * DP + c] = f2bf(t);
        if (OutF) OutF[row * DP + c] = t;
    }
}

// ---------------- GRU: sequential scan, 1 WG per sequence, 4 waves.
// W_hh in A-fragments (registers); h as 1-column B-fragment; 24 MFMAs/wave/step.
__global__ __launch_bounds__(256) void gru_k(
    const float* __restrict__ GX,                          // [2][SEQL][384] fp32
    const u16* __restrict__ WhhB,                          // [2][384][128] bf16 (converted)
    const float* __restrict__ Bhh1, const float* __restrict__ Bhh2,  // [384] fp32
    float* __restrict__ Hout)                              // [2][128] fp32
{
    const int s = blockIdx.x;
    const int lane = threadIdx.x & 63;
    const int wid  = threadIdx.x >> 6;
    const int m = lane & 15, q = lane >> 4;
    const u16* Whh = WhhB + (long)s * G3 * HN;
    const float* Bhh = s ? Bhh2 : Bhh1;
    const float* gx = GX + (long)s * SEQL * G3;

    __shared__ __align__(16) u16   hbf[HN];
    __shared__ __align__(16) float gh[G3];

    bf16x8 af[6][4];
    #pragma unroll
    for (int t6 = 0; t6 < 6; t6++)
        #pragma unroll
        for (int c = 0; c < 4; c++)
            af[t6][c] = *(const bf16x8*)(Whh + (wid * 96 + t6 * 16 + m) * HN + c * 32 + q * 8);

    const int i = threadIdx.x;
    float h = 0.f, bhr = 0.f, bhz = 0.f, bhn = 0.f;
    float gxr = 0.f, gxz = 0.f, gxn = 0.f;
    if (i < HN){
        bhr = Bhh[i]; bhz = Bhh[HN + i]; bhn = Bhh[2 * HN + i];
        hbf[i] = 0;
        gxr = gx[i]; gxz = gx[HN + i]; gxn = gx[2 * HN + i];
    }
    __syncthreads();

    const bf16x8 bzero = {0,0,0,0,0,0,0,0};
    const f32x4  zf    = {0.f,0.f,0.f,0.f};

    for (int t = 0; t < SEQL; t++){
        bf16x8 bf_[4];
        #pragma unroll
        for (int c = 0; c < 4; c++){
            bf16x8 hv = *(const bf16x8*)(hbf + c * 32 + q * 8);
            bf_[c] = (m == 0) ? hv : bzero;
        }
        f32x4 acc[6];
        #pragma unroll
        for (int t6 = 0; t6 < 6; t6++){
            f32x4 a = zf;
            #pragma unroll
            for (int c = 0; c < 4; c++) a = MFMA(af[t6][c], bf_[c], a);
            acc[t6] = a;
        }
        if (m == 0){
            #pragma unroll
            for (int t6 = 0; t6 < 6; t6++)
                *(f32x4*)(gh + wid * 96 + t6 * 16 + q * 4) = acc[t6];
        }
        __syncthreads();
        if (i < HN){
            float ghr = gh[i], ghz = gh[HN + i], ghn = gh[2 * HN + i];
            float r = 1.f / (1.f + __expf(-(gxr + ghr + bhr)));
            float z = 1.f / (1.f + __expf(-(gxz + ghz + bhz)));
            float narg = gxn + r * (ghn + bhn);
            float ea = __expf(-2.f * fabsf(narg));
            float n = copysignf((1.f - ea) / (1.f + ea), narg);
            h = (1.f - z) * n + z * h;
            hbf[i] = f2bf(h);
            if (t + 1 < SEQL){
                const float* g2 = gx + (long)(t + 1) * G3;
                gxr = g2[i]; gxz = g2[HN + i]; gxn = g2[2 * HN + i];
            }
        }
        __syncthreads();
    }
    if (i < HN) Hout[s * HN + i] = h;
}

// ---------------- head: fc1+relu, fc2, log_softmax -> 3 fp32
__global__ __launch_bounds__(256) void final_k(const float* __restrict__ Hout,
                                               const float* __restrict__ fc1w, const float* __restrict__ fc1b,
                                               const float* __restrict__ fc2w, const float* __restrict__ fc2b,
                                               float* __restrict__ out)
{
    __shared__ float hb[256];
    __shared__ float r1[256];
    __shared__ float lg[3];
    int tid = threadIdx.x;
    hb[tid] = Hout[tid];
    __syncthreads();
    float a = 0.f;
    for (int k2 = 0; k2 < 256; k2++) a += hb[k2] * fc1w[tid * 256 + k2];
    a += fc1b[tid];
    r1[tid] = fmaxf(a, 0.f);
    __syncthreads();
    if (tid < 3){
        float v = 0.f;
        for (int k2 = 0; k2 < 256; k2++) v += r1[k2] * fc2w[tid * 256 + k2];
        lg[tid] = v + fc2b[tid];
    }
    __syncthreads();
    if (tid == 0){
        float mx = fmaxf(lg[0], fmaxf(lg[1], lg[2]));
        float se = __expf(lg[0] - mx) + __expf(lg[1] - mx) + __expf(lg[2] - mx);
        float ls = mx + logf(se);
        out[0] = lg[0] - ls;
        out[1] = lg[1] - ls;
        out[2] = lg[2] - ls;
    }
}

extern "C" void kernel_launch(void* const* d_in, const int* in_sizes, int n_in,
                              void* d_out, int out_size, void* d_ws, size_t ws_size,
                              hipStream_t stream)
{
    (void)in_sizes; (void)n_in; (void)out_size; (void)ws_size;
    const float* x1     = (const float*)d_in[0];
    const float* x2     = (const float*)d_in[1];
    const float* q_w    = (const float*)d_in[2],  *q_b   = (const float*)d_in[3];
    const float* k_w    = (const float*)d_in[4],  *k_b   = (const float*)d_in[5];
    const float* v_w    = (const float*)d_in[6],  *v_b   = (const float*)d_in[7];
    const float* aln_g  = (const float*)d_in[8],  *aln_b = (const float*)d_in[9];
    const float* w_w    = (const float*)d_in[10], *w_b   = (const float*)d_in[11];
    const float* mln_g  = (const float*)d_in[12], *mln_b = (const float*)d_in[13];
    const float* g1_wih = (const float*)d_in[14], *g1_whh = (const float*)d_in[15];
    const float* g1_bih = (const float*)d_in[16], *g1_bhh = (const float*)d_in[17];
    const float* g2_wih = (const float*)d_in[18], *g2_whh = (const float*)d_in[19];
    const float* g2_bih = (const float*)d_in[20], *g2_bhh = (const float*)d_in[21];
    const float* fc1w   = (const float*)d_in[22], *fc1b  = (const float*)d_in[23];
    const float* fc2w   = (const float*)d_in[24], *fc2b  = (const float*)d_in[25];

    char* wsp = (char*)d_ws;
    auto alloc = [&](size_t bytes) -> char* {
        char* p = wsp; wsp += (bytes + 255) & ~(size_t)255; return p;
    };
    float* XF   = (float*)alloc(2L * SEQL * DP * 4);   // fp32 stack input (residual for aln)
    u16*   CUR  = (u16*)  alloc(2L * SEQL * DP * 2);   // bf16 stack input (MFMA operand)
    u16*   Hb   = (u16*)  alloc(2L * SEQL * DP * 2);   // LN1 output bf16
    float* Of   = (float*)alloc(2L * SEQL * DP * 4);   // fp32 scratch (attn out / W-proj out)
    u16*   Wpk  = (u16*)  alloc(4L * DP * DP * 2);     // q,k,v,w packed bf16 [320][320]
    u16*   GWpk = (u16*)  alloc(2L * G3 * DP * 2);     // g{1,2}_wih packed bf16 [384][320]
    u16*   WhhB = (u16*)  alloc(2L * G3 * HN * 2);     // g{1,2}_whh bf16 [384][128]
    float* Hout = (float*)alloc(2L * HN * 4);
    // union block: {QK slices + VT}  vs  GX (used after attention)
    u16*   QK   = (u16*)  alloc(2L * 2 * SEQL * DP * 2 + 2L * DP * SEQL * 2);
    u16*   VT   = QK + 2L * 2 * SEQL * DP;
    float* GX   = (float*)QK;                          // [2][SEQL][384] fp32, aliases QK/VT

    const long SL  = (long)SEQL * DP;     // per-seq activation stride (elements)
    const long SLC = 2L * SEQL * DP;      // per-slice stride in QK

    // prep
    pad_x<<<256, 256, 0, stream>>>(x1, XF,      CUR);
    pad_x<<<256, 256, 0, stream>>>(x2, XF + SL, CUR + SL);
    cvt_pad<<<128, 256, 0, stream>>>(q_w, Wpk,                VECT, VECT, DP, DP);
    cvt_pad<<<128, 256, 0, stream>>>(k_w, Wpk + 1L * DP * DP, VECT, VECT, DP, DP);
    cvt_pad<<<128, 256, 0, stream>>>(v_w, Wpk + 2L * DP * DP, VECT, VECT, DP, DP);
    cvt_pad<<<128, 256, 0, stream>>>(w_w, Wpk + 3L * DP * DP, VECT, VECT, DP, DP);
    cvt_pad<<<128, 256, 0, stream>>>(g1_wih, GWpk,                 G3, VECT, G3, DP);
    cvt_pad<<<128, 256, 0, stream>>>(g2_wih, GWpk + (long)G3 * DP, G3, VECT, G3, DP);
    cvt_pad<<<64, 256, 0, stream>>>(g1_whh, WhhB,                 G3, HN, G3, HN);
    cvt_pad<<<64, 256, 0, stream>>>(g2_whh, WhhB + (long)G3 * HN, G3, HN, G3, HN);

    for (int st = 0; st < 3; ++st){
        // Q,K projections (2 slices x 2 seqs) -> QK ; V -> VT (transposed store)
        gemm_k<NQT, 0, false><<<dim3(SEQL / 128, 2, 2), 256, 0, stream>>>(
            CUR, Wpk, q_b, k_b, nullptr, VECT, QK);
        gemm_k<NQT, 2, false><<<dim3(SEQL / 128, 1, 2), 256, 0, stream>>>(
            CUR, Wpk + 2L * DP * DP, v_b, nullptr, nullptr, VECT, VT);
        flash_k<<<dim3(SEQL / 64, 1, 2), 256, 0, stream>>>(QK, QK + SLC, VT, Of);
        ln_k<<<dim3(2 * SEQL / 4), 256, 0, stream>>>(Of, XF, XF + SL, DP, aln_g, aln_b, Hb, nullptr);
        gemm_k<NQT, 1, false><<<dim3(SEQL / 128, 1, 2), 256, 0, stream>>>(
            Hb, Wpk + 3L * DP * DP, w_b, nullptr, nullptr, VECT, Of);
        ln_k<<<dim3(2 * SEQL / 4), 256, 0, stream>>>(Of, x1, x2, VECT, mln_g, mln_b, CUR, XF);
    }

    // GRU input projections (weight/bias per seq) -> GX (aliases QK/VT, now dead)
    gemm_k<24, 1, true><<<dim3(SEQL / 128, 1, 2), 256, 0, stream>>>(
        CUR, GWpk, g1_bih, g2_bih, nullptr, G3, GX);
    gru_k<<<dim3(2), 256, 0, stream>>>(GX, WhhB, g1_bhh, g2_bhh, Hout);
    final_k<<<dim3(1), 256, 0, stream>>>(Hout, fc1w, fc1b, fc2w, fc2b, (float*)d_out);
}

// Round 3
// 4148.719 us; speedup vs baseline: 1.2370x; 1.2370x over previous
//
#include <hip/hip_runtime.h>
#include <hip/hip_bf16.h>

// Problem constants
#define SEQL 4096
#define VECT 300
#define DP   320     // padded feature dim (k-dim), 10 chunks of 32
#define NQT  20      // n-tiles (320 cols) for projection GEMMs
#define HN   128
#define G3   384     // 3*H
#define JC   4       // flash j-chunks (split-K over key dim)

typedef unsigned short u16;
typedef __attribute__((ext_vector_type(8))) short bf16x8;  // 8 bf16 = 4 VGPRs
typedef __attribute__((ext_vector_type(4))) float f32x4;

#define MFMA(a,b,c) __builtin_amdgcn_mfma_f32_16x16x32_bf16(a,b,c,0,0,0)
// Verified layouts (learn_hip m89/m91/m120):
//   A[m][k]: m=lane&15, k=(lane>>4)*8+j
//   B[k][n]: n=lane&15, k=(lane>>4)*8+j
//   C/D[row][col]: col=lane&15, row=(lane>>4)*4+reg

#define L2E 1.44269504088896f

__device__ __forceinline__ float bf2f(u16 v){
    union { unsigned u; float f; } t; t.u = ((unsigned)v) << 16; return t.f;
}
__device__ __forceinline__ u16 f2bf(float f){
    union { float f; unsigned u; } t; t.f = f;
    return (u16)((t.u + 0x7FFFu + ((t.u >> 16) & 1u)) >> 16);
}
__device__ __forceinline__ float sigm_f(float x){
    return __builtin_amdgcn_rcpf(1.f + __builtin_amdgcn_exp2f(-L2E * x));
}
__device__ __forceinline__ float tanh_f(float x){
    return fmaf(2.f, __builtin_amdgcn_rcpf(1.f + __builtin_amdgcn_exp2f(-2.f * L2E * x)), -1.f);
}

// ---------------- fp32 [R][C] -> bf16 padded [Rp][Cp], optional scale
__global__ __launch_bounds__(256) void cvt_pad(const float* __restrict__ src,
                                               u16* __restrict__ dst,
                                               int R, int C, int Rp, int Cp, float scale)
{
    int n = Rp * Cp;
    for (int i = blockIdx.x * blockDim.x + threadIdx.x; i < n; i += gridDim.x * blockDim.x){
        int r = i / Cp, c = i - r * Cp;
        float v = (r < R && c < C) ? src[r * C + c] * scale : 0.f;
        dst[i] = f2bf(v);
    }
}

// ---------------- fp32 vector scale-copy
__global__ __launch_bounds__(256) void scale_copy(const float* __restrict__ src,
                                                  float* __restrict__ dst, int n, float scale)
{
    int i = blockIdx.x * blockDim.x + threadIdx.x;
    if (i < n) dst[i] = src[i] * scale;
}

// ---------------- x: fp32 [S][300] -> XF fp32 [S][320] + CUR bf16 [S][320]
__global__ __launch_bounds__(256) void pad_x(const float* __restrict__ src,
                                             float* __restrict__ xf, u16* __restrict__ cur)
{
    int n = SEQL * DP;
    for (int i = blockIdx.x * blockDim.x + threadIdx.x; i < n; i += gridDim.x * blockDim.x){
        int r = i / DP, c = i - r * DP;
        float v = (c < VECT) ? src[r * VECT + c] : 0.f;
        xf[i]  = v;
        cur[i] = f2bf(v);
    }
}

// ---------------- GEMM: Y[s][i][col] = sum_d A[s][i][d] * W[wsel][col][d] + bias[col]
// 256 thr = 4 waves; wave handles 16 rows; WG = 64 rows.
// OM: 1 = fp32 row-major; 3 = QKV fused: slices 0,1 bf16 row-major, slice 2 bf16 transposed.
template<int NT, int OM, bool WPERSEQ>
__global__ __launch_bounds__(256) void gemm_k(
    const u16* __restrict__ A, const u16* __restrict__ Wp,
    const float* __restrict__ b0, const float* __restrict__ b1, const float* __restrict__ b2,
    int nb, void* __restrict__ Out)
{
    const int lane = threadIdx.x & 63;
    const int wid  = threadIdx.x >> 6;
    const int s    = blockIdx.z;
    const int sl   = blockIdx.y;
    const int wsel = WPERSEQ ? s : sl;
    const int row0 = blockIdx.x * 64 + wid * 16;
    const int m    = lane & 15;
    const int q    = lane >> 4;

    const u16* Arow = A + ((long)s * SEQL + row0) * DP;
    const u16* W    = Wp + (long)wsel * (NT * 16) * DP;

    f32x4 zf = {0.f, 0.f, 0.f, 0.f};
    f32x4 acc[NT];
    #pragma unroll
    for (int n = 0; n < NT; n++) acc[n] = zf;

    for (int c = 0; c < DP / 32; ++c){
        const int koff = c * 32 + q * 8;
        bf16x8 a0 = *(const bf16x8*)(Arow + m * DP + koff);
        #pragma unroll
        for (int n = 0; n < NT; n++){
            bf16x8 b = *(const bf16x8*)(W + (n * 16 + m) * DP + koff);
            acc[n] = MFMA(a0, b, acc[n]);
        }
    }

    const int bsel = WPERSEQ ? s : sl;
    const float* bp = (bsel == 0) ? b0 : ((bsel == 1) ? b1 : b2);
    const long SLC = 2L * SEQL * DP;  // per-slice stride in QKV buffer

    #pragma unroll
    for (int n = 0; n < NT; n++){
        int col = n * 16 + m;
        float bv = (col < nb) ? bp[col] : 0.f;
        #pragma unroll
        for (int r = 0; r < 4; r++){
            long row = row0 + q * 4 + r;
            float v = acc[n][r] + bv;
            if (OM == 1){
                long off = ((long)s * SEQL + row) * (long)(NT * 16) + col;
                ((float*)Out)[off] = v;
            } else {  // OM == 3
                long off;
                if (sl < 2) off = ((long)(sl * 2 + s) * SEQL + row) * DP + col;
                else        off = 2 * SLC + ((long)s * DP + col) * SEQL + row;
                ((u16*)Out)[off] = f2bf(v);
            }
        }
    }
}

// ---------------- flash attention chunk: Onum = exp(QK^T*scale - 16) V (unnormalized),
// Lp = row sums. Q pre-scaled is NOT used; scale folded into exp2 constants.
// grid (SEQL/64, JC, 2); WG 256 = 4 waves, wave owns 16 Q-rows, chunk = 1024 keys.
__global__ __launch_bounds__(256) void flash_k(
    const u16* __restrict__ Q, const u16* __restrict__ K, const u16* __restrict__ VT,
    u16* __restrict__ Onum, float* __restrict__ Lp)
{
    const int lane = threadIdx.x & 63;
    const int wid  = threadIdx.x >> 6;
    const int s    = blockIdx.z;
    const int jc   = blockIdx.y;
    const int row0 = blockIdx.x * 64 + wid * 16;
    const int m = lane & 15, q = lane >> 4;

    __shared__ __align__(16) u16 pbuf_all[4][16 * 72];
    u16* pbuf = pbuf_all[wid];

    const u16* Qb  = Q  + ((long)s * SEQL + row0) * DP;
    const u16* Kb  = K  + (long)s * SEQL * DP;
    const u16* VTb = VT + (long)s * DP * SEQL;

    bf16x8 qf[10];
    #pragma unroll
    for (int c = 0; c < 10; c++)
        qf[c] = *(const bf16x8*)(Qb + m * DP + c * 32 + q * 8);

    f32x4 zf = {0.f, 0.f, 0.f, 0.f};
    f32x4 oacc[NQT];
    #pragma unroll
    for (int n = 0; n < NQT; n++) oacc[n] = zf;
    float lacc[4] = {0.f, 0.f, 0.f, 0.f};

    const float K2 = 0.057735026918962576f * L2E;  // scale * log2(e)
    const float MB = -16.f * L2E;                   // fixed max offset (scores bounded ~|4|)

    for (int j = jc * 32; j < jc * 32 + 32; ++j){
        f32x4 sA = zf, sB = zf;
        #pragma unroll
        for (int c = 0; c < 10; c++){
            const int koff = c * 32 + q * 8;
            bf16x8 kA = *(const bf16x8*)(Kb + (long)(j * 32 +      m) * DP + koff);
            bf16x8 kB = *(const bf16x8*)(Kb + (long)(j * 32 + 16 + m) * DP + koff);
            sA = MFMA(qf[c], kA, sA);
            sB = MFMA(qf[c], kB, sB);
        }
        #pragma unroll
        for (int r = 0; r < 4; r++){
            float a = __builtin_amdgcn_exp2f(fmaf(sA[r], K2, MB));
            float b = __builtin_amdgcn_exp2f(fmaf(sB[r], K2, MB));
            lacc[r] += a + b;
            pbuf[(q * 4 + r) * 72 +      m] = f2bf(a);
            pbuf[(q * 4 + r) * 72 + 16 + m] = f2bf(b);
        }
        asm volatile("s_waitcnt lgkmcnt(0)" ::: "memory");
        bf16x8 pf = *(const bf16x8*)(pbuf + m * 72 + q * 8);

        #pragma unroll
        for (int n = 0; n < NQT; n++){
            bf16x8 vb = *(const bf16x8*)(VTb + (long)(n * 16 + m) * SEQL + j * 32 + q * 8);
            oacc[n] = MFMA(pf, vb, oacc[n]);
        }
    }

    // reduce l over the 16 m-lanes (columns)
    #pragma unroll
    for (int r = 0; r < 4; r++){
        float t = lacc[r];
        t += __shfl_xor(t, 1); t += __shfl_xor(t, 2);
        t += __shfl_xor(t, 4); t += __shfl_xor(t, 8);
        lacc[r] = t;
    }
    const long grow0 = (long)s * SEQL + row0;   // global row base (0..2S)
    if (m == 0){
        #pragma unroll
        for (int r = 0; r < 4; r++)
            Lp[(long)jc * 2 * SEQL + grow0 + q * 4 + r] = lacc[r];
    }
    u16* Ob = Onum + ((long)jc * 2 * SEQL + grow0) * DP;
    #pragma unroll
    for (int n = 0; n < NQT; n++)
        #pragma unroll
        for (int r = 0; r < 4; r++)
            Ob[(long)(q * 4 + r) * DP + n * 16 + m] = f2bf(oacc[n][r]);
}

// ---------------- combine chunks + LayerNorm1: out = LN(sum(Onum)/sum(l) + XF) * g + b
__global__ __launch_bounds__(256) void lncomb_k(const u16* __restrict__ Onum, const float* __restrict__ Lp,
                                                const float* __restrict__ XF,
                                                const float* __restrict__ g, const float* __restrict__ b,
                                                u16* __restrict__ OutB)
{
    long row = (long)((blockIdx.x * blockDim.x + threadIdx.x) >> 6);
    int lane = threadIdx.x & 63;
    if (row >= 2L * SEQL) return;
    float l = 0.f;
    #pragma unroll
    for (int jc = 0; jc < JC; jc++) l += Lp[(long)jc * 2 * SEQL + row];
    float inv = 1.f / l;
    const float* xr = XF + row * DP;
    float v[5], sum = 0.f, sq = 0.f;
    #pragma unroll
    for (int i = 0; i < 5; i++){
        int c = lane + i * 64;
        float o = 0.f;
        #pragma unroll
        for (int jc = 0; jc < JC; jc++)
            o += bf2f(Onum[((long)jc * 2 * SEQL + row) * DP + c]);
        float t = (c < VECT) ? (o * inv + xr[c]) : 0.f;
        v[i] = t; sum += t; sq += t * t;
    }
    #pragma unroll
    for (int o = 1; o < 64; o <<= 1){ sum += __shfl_xor(sum, o); sq += __shfl_xor(sq, o); }
    float mean = sum / VECT;
    float var  = sq / VECT - mean * mean;
    float rstd = rsqrtf(var + 1e-5f);
    #pragma unroll
    for (int i = 0; i < 5; i++){
        int c = lane + i * 64;
        float t = (c < VECT) ? ((v[i] - mean) * rstd * g[c] + b[c]) : 0.f;
        OutB[row * DP + c] = f2bf(t);
    }
}

// ---------------- LayerNorm2: out = LN(Xf + Res) * g + b ; OutB bf16 + OutF fp32
__global__ __launch_bounds__(256) void ln_k(const float* __restrict__ Xf,
                                            const float* __restrict__ Res0, const float* __restrict__ Res1,
                                            int rstride,
                                            const float* __restrict__ g, const float* __restrict__ b,
                                            u16* __restrict__ OutB, float* __restrict__ OutF)
{
    long row = (long)((blockIdx.x * blockDim.x + threadIdx.x) >> 6);
    int lane = threadIdx.x & 63;
    if (row >= 2L * SEQL) return;
    const float* xr = Xf + row * DP;
    const float* rr = (row < SEQL) ? (Res0 + row * (long)rstride)
                                   : (Res1 + (row - SEQL) * (long)rstride);
    float v[5], sum = 0.f, sq = 0.f;
    #pragma unroll
    for (int i = 0; i < 5; i++){
        int c = lane + i * 64;
        float t = (c < VECT) ? (xr[c] + rr[c]) : 0.f;
        v[i] = t; sum += t; sq += t * t;
    }
    #pragma unroll
    for (int o = 1; o < 64; o <<= 1){ sum += __shfl_xor(sum, o); sq += __shfl_xor(sq, o); }
    float mean = sum / VECT;
    float var  = sq / VECT - mean * mean;
    float rstd = rsqrtf(var + 1e-5f);
    #pragma unroll
    for (int i = 0; i < 5; i++){
        int c = lane + i * 64;
        float t = (c < VECT) ? ((v[i] - mean) * rstd * g[c] + b[c]) : 0.f;
        OutB[row * DP + c] = f2bf(t);
        if (OutF) OutF[row * DP + c] = t;
    }
}

// ---------------- GRU: sequential scan, 1 WG per sequence, 4 waves, ONE barrier/step.
// W_hh rows wid*96..+96 in A-frags; h replicated into all 16 B-columns via ds_bpermute;
// gh slice written to double-buffered LDS; gate math redundant per wave (2 h per lane).
__global__ __launch_bounds__(256) void gru_k(
    const float* __restrict__ GX,                          // [2][SEQL][384] fp32
    const u16* __restrict__ WhhB,                          // [2][384][128] bf16
    const float* __restrict__ Bhh1, const float* __restrict__ Bhh2,
    float* __restrict__ Hout)                              // [2][128] fp32
{
    const int s = blockIdx.x;
    const int lane = threadIdx.x & 63;
    const int wid  = threadIdx.x >> 6;
    const int m = lane & 15, q = lane >> 4;
    const u16* Whh = WhhB + (long)s * G3 * HN;
    const float* Bhh = s ? Bhh2 : Bhh1;
    const float* gx = GX + (long)s * SEQL * G3;

    __shared__ __align__(16) float ghb[2][G3];

    bf16x8 af[6][4];
    #pragma unroll
    for (int t6 = 0; t6 < 6; t6++)
        #pragma unroll
        for (int c = 0; c < 4; c++)
            af[t6][c] = *(const bf16x8*)(Whh + (wid * 96 + t6 * 16 + m) * HN + c * 32 + q * 8);

    const int i0 = 2 * lane, i1 = i0 + 1;
    const float bhr0 = Bhh[i0],        bhr1 = Bhh[i1];
    const float bhz0 = Bhh[HN + i0],   bhz1 = Bhh[HN + i1];
    const float bhn0 = Bhh[2*HN + i0], bhn1 = Bhh[2*HN + i1];

    float2 gr = *(const float2*)(gx + i0);
    float2 gz = *(const float2*)(gx + HN + i0);
    float2 gn = *(const float2*)(gx + 2*HN + i0);

    float h0 = 0.f, h1 = 0.f;
    unsigned hpk = 0;
    const f32x4 zf = {0.f, 0.f, 0.f, 0.f};

    for (int t = 0; t < SEQL; t++){
        // B-frags: replicate h into all 16 columns (pairs via bpermute)
        bf16x8 bf_[4];
        #pragma unroll
        for (int c = 0; c < 4; c++){
            union { unsigned u[4]; bf16x8 v; } bu;
            #pragma unroll
            for (int jj = 0; jj < 4; jj++)
                bu.u[jj] = (unsigned)__builtin_amdgcn_ds_bpermute((c * 16 + q * 4 + jj) * 4, (int)hpk);
            bf_[c] = bu.v;
        }
        // prefetch gx for t+1
        int tn = (t + 1 < SEQL) ? t + 1 : t;
        const float* gxn_p = gx + (long)tn * G3;
        float2 nr = *(const float2*)(gxn_p + i0);
        float2 nz = *(const float2*)(gxn_p + HN + i0);
        float2 nn = *(const float2*)(gxn_p + 2*HN + i0);

        f32x4 acc[6];
        #pragma unroll
        for (int t6 = 0; t6 < 6; t6++){
            f32x4 a = zf;
            #pragma unroll
            for (int c = 0; c < 4; c++) a = MFMA(af[t6][c], bf_[c], a);
            acc[t6] = a;
        }
        // every lane holds rows wid*96+t6*16+q*4+r (cols identical); lanes m==0 write
        if (m == 0){
            #pragma unroll
            for (int t6 = 0; t6 < 6; t6++)
                *(f32x4*)(&ghb[t & 1][wid * 96 + t6 * 16 + q * 4]) = acc[t6];
        }
        __syncthreads();
        const float* gb = ghb[t & 1];
        float2 ghr = *(const float2*)(gb + i0);
        float2 ghz = *(const float2*)(gb + HN + i0);
        float2 ghn = *(const float2*)(gb + 2*HN + i0);

        float r0 = sigm_f(gr.x + ghr.x + bhr0);
        float r1 = sigm_f(gr.y + ghr.y + bhr1);
        float z0 = sigm_f(gz.x + ghz.x + bhz0);
        float z1 = sigm_f(gz.y + ghz.y + bhz1);
        float n0 = tanh_f(gn.x + r0 * (ghn.x + bhn0));
        float n1 = tanh_f(gn.y + r1 * (ghn.y + bhn1));
        h0 = (1.f - z0) * n0 + z0 * h0;
        h1 = (1.f - z1) * n1 + z1 * h1;
        hpk = ((unsigned)f2bf(h1) << 16) | (unsigned)f2bf(h0);
        gr = nr; gz = nz; gn = nn;
    }
    if (wid == 0){
        Hout[s * HN + i0] = h0;
        Hout[s * HN + i1] = h1;
    }
}

// ---------------- head: fc1+relu, fc2, log_softmax -> 3 fp32
__global__ __launch_bounds__(256) void final_k(const float* __restrict__ Hout,
                                               const float* __restrict__ fc1w, const float* __restrict__ fc1b,
                                               const float* __restrict__ fc2w, const float* __restrict__ fc2b,
                                               float* __restrict__ out)
{
    __shared__ float hb[256];
    __shared__ float r1[256];
    __shared__ float lg[3];
    int tid = threadIdx.x;
    hb[tid] = Hout[tid];
    __syncthreads();
    float a = 0.f;
    for (int k2 = 0; k2 < 256; k2++) a += hb[k2] * fc1w[tid * 256 + k2];
    a += fc1b[tid];
    r1[tid] = fmaxf(a, 0.f);
    __syncthreads();
    if (tid < 3){
        float v = 0.f;
        for (int k2 = 0; k2 < 256; k2++) v += r1[k2] * fc2w[tid * 256 + k2];
        lg[tid] = v + fc2b[tid];
    }
    __syncthreads();
    if (tid == 0){
        float mx = fmaxf(lg[0], fmaxf(lg[1], lg[2]));
        float se = __expf(lg[0] - mx) + __expf(lg[1] - mx) + __expf(lg[2] - mx);
        float ls = mx + logf(se);
        out[0] = lg[0] - ls;
        out[1] = lg[1] - ls;
        out[2] = lg[2] - ls;
    }
}

extern "C" void kernel_launch(void* const* d_in, const int* in_sizes, int n_in,
                              void* d_out, int out_size, void* d_ws, size_t ws_size,
                              hipStream_t stream)
{
    (void)in_sizes; (void)n_in; (void)out_size; (void)ws_size;
    const float* x1     = (const float*)d_in[0];
    const float* x2     = (const float*)d_in[1];
    const float* q_w    = (const float*)d_in[2],  *q_b   = (const float*)d_in[3];
    const float* k_w    = (const float*)d_in[4],  *k_b   = (const float*)d_in[5];
    const float* v_w    = (const float*)d_in[6],  *v_b   = (const float*)d_in[7];
    const float* aln_g  = (const float*)d_in[8],  *aln_b = (const float*)d_in[9];
    const float* w_w    = (const float*)d_in[10], *w_b   = (const float*)d_in[11];
    const float* mln_g  = (const float*)d_in[12], *mln_b = (const float*)d_in[13];
    const float* g1_wih = (const float*)d_in[14], *g1_whh = (const float*)d_in[15];
    const float* g1_bih = (const float*)d_in[16], *g1_bhh = (const float*)d_in[17];
    const float* g2_wih = (const float*)d_in[18], *g2_whh = (const float*)d_in[19];
    const float* g2_bih = (const float*)d_in[20], *g2_bhh = (const float*)d_in[21];
    const float* fc1w   = (const float*)d_in[22], *fc1b  = (const float*)d_in[23];
    const float* fc2w   = (const float*)d_in[24], *fc2b  = (const float*)d_in[25];

    char* wsp = (char*)d_ws;
    auto alloc = [&](size_t bytes) -> char* {
        char* p = wsp; wsp += (bytes + 255) & ~(size_t)255; return p;
    };
    float* XF   = (float*)alloc(2L * SEQL * DP * 4);   // fp32 stack input (residual for aln)
    u16*   CUR  = (u16*)  alloc(2L * SEQL * DP * 2);   // bf16 stack input (MFMA operand)
    u16*   Hb   = (u16*)  alloc(2L * SEQL * DP * 2);   // LN1 output bf16
    u16*   Wpk  = (u16*)  alloc(4L * DP * DP * 2);     // q(scaled),k,v,w packed bf16 [320][320]
    u16*   GWpk = (u16*)  alloc(2L * G3 * DP * 2);     // g{1,2}_wih packed bf16 [384][320]
    u16*   WhhB = (u16*)  alloc(2L * G3 * HN * 2);     // g{1,2}_whh bf16 [384][128]
    float* qbS  = (float*)alloc(DP * 4);               // scaled q bias
    float* Hout = (float*)alloc(2L * HN * 4);
    float* Lp   = (float*)alloc((long)JC * 2 * SEQL * 4);
    // union1: {QK 2 slices + VT} vs GX
    size_t u1 = (2L * 2 * SEQL * DP + 2L * DP * SEQL) * 2;
    size_t u1b = 2L * SEQL * G3 * 4;
    u16*   QKV  = (u16*)  alloc(u1 > u1b ? u1 : u1b);
    u16*   VT   = QKV + 2L * 2 * SEQL * DP;
    float* GX   = (float*)QKV;
    // union2: Opart (flash numerator partials, bf16) vs Of (fp32 W-proj out)
    size_t u2 = (long)JC * 2 * SEQL * DP * 2;
    size_t u2b = 2L * SEQL * DP * 4;
    u16*   Onum = (u16*)  alloc(u2 > u2b ? u2 : u2b);
    float* Of   = (float*)Onum;

    const float scale = 0.057735026918962576f;  // 1/sqrt(300)

    // prep
    pad_x<<<256, 256, 0, stream>>>(x1, XF,                  CUR);
    pad_x<<<256, 256, 0, stream>>>(x2, XF + (long)SEQL*DP,  CUR + (long)SEQL*DP);
    cvt_pad<<<128, 256, 0, stream>>>(q_w, Wpk,                VECT, VECT, DP, DP, 1.f);
    cvt_pad<<<128, 256, 0, stream>>>(k_w, Wpk + 1L * DP * DP, VECT, VECT, DP, DP, 1.f);
    cvt_pad<<<128, 256, 0, stream>>>(v_w, Wpk + 2L * DP * DP, VECT, VECT, DP, DP, 1.f);
    cvt_pad<<<128, 256, 0, stream>>>(w_w, Wpk + 3L * DP * DP, VECT, VECT, DP, DP, 1.f);
    cvt_pad<<<128, 256, 0, stream>>>(g1_wih, GWpk,                 G3, VECT, G3, DP, 1.f);
    cvt_pad<<<128, 256, 0, stream>>>(g2_wih, GWpk + (long)G3 * DP, G3, VECT, G3, DP, 1.f);
    cvt_pad<<<64, 256, 0, stream>>>(g1_whh, WhhB,                 G3, HN, G3, HN, 1.f);
    cvt_pad<<<64, 256, 0, stream>>>(g2_whh, WhhB + (long)G3 * HN, G3, HN, G3, HN, 1.f);
    scale_copy<<<2, 256, 0, stream>>>(q_b, qbS, VECT, 1.f);

    for (int st = 0; st < 3; ++st){
        // Q,K -> QKV slices 0,1 ; V -> transposed at slice 2 (VT)
        gemm_k<NQT, 3, false><<<dim3(SEQL / 64, 3, 2), 256, 0, stream>>>(
            CUR, Wpk, qbS, k_b, v_b, VECT, QKV);
        flash_k<<<dim3(SEQL / 64, JC, 2), 256, 0, stream>>>(QKV, QKV + 2L*SEQL*DP, VT, Onum, Lp);
        lncomb_k<<<dim3(2 * SEQL / 4), 256, 0, stream>>>(Onum, Lp, XF, aln_g, aln_b, Hb);
        gemm_k<NQT, 1, false><<<dim3(SEQL / 64, 1, 2), 256, 0, stream>>>(
            Hb, Wpk + 3L * DP * DP, w_b, nullptr, nullptr, VECT, Of);
        ln_k<<<dim3(2 * SEQL / 4), 256, 0, stream>>>(Of, x1, x2, VECT, mln_g, mln_b, CUR, XF);
    }

    // GRU input projections (weight/bias per seq) -> GX (aliases QKV, now dead)
    gemm_k<24, 1, true><<<dim3(SEQL / 64, 1, 2), 256, 0, stream>>>(
        CUR, GWpk, g1_bih, g2_bih, nullptr, G3, GX);
    gru_k<<<dim3(2), 256, 0, stream>>>(GX, WhhB, g1_bhh, g2_bhh, Hout);
    final_k<<<dim3(1), 256, 0, stream>>>(Hout, fc1w, fc1b, fc2w, fc2b, (float*)d_out);
}